// Round 1
// baseline (22.452 us; speedup 1.0000x reference)
//
#include <hip/hip_runtime.h>
#include <hip/hip_bf16.h>

// Problem constants (match reference)
#define MB 4096      // B rows
#define MD 4096      // D classes
#define MP 8         // P positives per row
#define MARGIN 0.5f

// Stage 1: one block per row. Computes
//   sum_{d not in pos set} sum_k relu(MARGIN + x[i,d] - x[i,pos[k]])
// and writes the per-row partial to ws[row].
__global__ __launch_bounds__(256) void margin_rows_kernel(
    const float* __restrict__ x,
    const int* __restrict__ pos_ids,
    float* __restrict__ ws)
{
    const int row = blockIdx.x;
    const int t = threadIdx.x;
    const float* __restrict__ xr = x + (size_t)row * MD;

    __shared__ float s_xp[MP];
    __shared__ int   s_pi[MP];
    if (t < MP) {
        int p = pos_ids[row * MP + t];
        s_pi[t] = p;
        s_xp[t] = xr[p];
    }
    __syncthreads();

    float xp[MP];
    int   pi[MP];
#pragma unroll
    for (int k = 0; k < MP; ++k) { xp[k] = s_xp[k]; pi[k] = s_pi[k]; }

    float acc = 0.0f;
    // 4096 cols / 256 threads = 16 cols/thread as 4 x float4 (coalesced)
#pragma unroll
    for (int it = 0; it < 4; ++it) {
        const int d0 = it * 1024 + t * 4;
        const float4 v = *reinterpret_cast<const float4*>(xr + d0);
        const float vv[4] = { v.x, v.y, v.z, v.w };
#pragma unroll
        for (int j = 0; j < 4; ++j) {
            const int d = d0 + j;
            bool is_neg = true;
#pragma unroll
            for (int k = 0; k < MP; ++k) is_neg = is_neg && (d != pi[k]);
            if (is_neg) {
                float s = 0.0f;
#pragma unroll
                for (int k = 0; k < MP; ++k)
                    s += fmaxf(0.0f, MARGIN + vv[j] - xp[k]);
                acc += s;
            }
        }
    }

    // wave (64-lane) shuffle reduce
#pragma unroll
    for (int off = 32; off > 0; off >>= 1)
        acc += __shfl_down(acc, off, 64);

    __shared__ float s_part[4];
    const int wave = t >> 6;
    if ((t & 63) == 0) s_part[wave] = acc;
    __syncthreads();
    if (t == 0)
        ws[row] = s_part[0] + s_part[1] + s_part[2] + s_part[3];
}

// Stage 2: one block reduces MB partials (double accumulation) and scales.
__global__ __launch_bounds__(256) void margin_final_kernel(
    const float* __restrict__ ws,
    float* __restrict__ out)
{
    const int t = threadIdx.x;
    double acc = 0.0;
    // 4096 / 256 = 16 partials per thread
#pragma unroll
    for (int it = 0; it < 16; ++it)
        acc += (double)ws[it * 256 + t];

#pragma unroll
    for (int off = 32; off > 0; off >>= 1)
        acc += __shfl_down(acc, off, 64);

    __shared__ double s_part[4];
    const int wave = t >> 6;
    if ((t & 63) == 0) s_part[wave] = acc;
    __syncthreads();
    if (t == 0) {
        const double tot = s_part[0] + s_part[1] + s_part[2] + s_part[3];
        const double count = (double)MB * (double)MP * (double)(MD - MP);
        out[0] = (float)(tot / count);
    }
}

extern "C" void kernel_launch(void* const* d_in, const int* in_sizes, int n_in,
                              void* d_out, int out_size, void* d_ws, size_t ws_size,
                              hipStream_t stream) {
    const float* x = (const float*)d_in[0];
    // d_in[1] is y, redundant with pos_ids — not read (halves HBM traffic).
    const int* pos_ids = (const int*)d_in[2];
    float* out = (float*)d_out;
    float* ws = (float*)d_ws;  // MB floats = 16 KB of scratch

    margin_rows_kernel<<<MB, 256, 0, stream>>>(x, pos_ids, ws);
    margin_final_kernel<<<1, 256, 0, stream>>>(ws, out);
}

// Round 3
// 19.743 us; speedup vs baseline: 1.1372x; 1.1372x over previous
//
#include <hip/hip_runtime.h>
#include <hip/hip_bf16.h>

// Problem constants (match reference)
#define MB 4096      // B rows
#define MD 4096      // D classes
#define MP 8         // P positives per row
#define MARGIN 0.5f

typedef float f32x4 __attribute__((ext_vector_type(4)));

// Stage 1: one block (256 threads) per row.
// Computes  sum_{all d} sum_k relu(MARGIN + x[i,d] - x[i,pos[k]])
// then subtracts the positive-column contribution
//   corr = sum_{distinct d in pos set} sum_k relu(MARGIN + x[i,d] - x[i,pos[k]])
// which only depends on the 8 anchor scores. This removes all per-column
// masking compares/branches from the hot loop (40 -> 24 VALU ops per column).
__global__ __launch_bounds__(256) void margin_rows_kernel(
    const float* __restrict__ x,
    const int* __restrict__ pos_ids,
    float* __restrict__ ws)
{
    const int row = blockIdx.x;
    const int t = threadIdx.x;
    const int lane = t & 63;
    const float* __restrict__ xr = x + (size_t)row * MD;

    // Longest dependency chain first: pos_ids -> gather -> shfl broadcast.
    const int p = pos_ids[row * MP + (lane & 7)];

    // Independent streaming loads — issue early, overlap with the gather.
    const f32x4* __restrict__ xr4 = reinterpret_cast<const f32x4*>(xr);
    const f32x4 v0 = __builtin_nontemporal_load(xr4 + t);
    const f32x4 v1 = __builtin_nontemporal_load(xr4 + 256 + t);
    const f32x4 v2 = __builtin_nontemporal_load(xr4 + 512 + t);
    const f32x4 v3 = __builtin_nontemporal_load(xr4 + 768 + t);

    const float xg = xr[p];   // 8 unique addresses per wave (L1/L2 hits)

    // Per-wave broadcast of thresholds t_k = x[pos_k] - MARGIN (no barrier).
    float th[MP];
    int   pi[MP];
#pragma unroll
    for (int k = 0; k < MP; ++k) {
        th[k] = __shfl(xg, k, 64) - MARGIN;
        pi[k] = __shfl(p, k, 64);
    }

    const float vv[16] = { v0.x, v0.y, v0.z, v0.w,
                           v1.x, v1.y, v1.z, v1.w,
                           v2.x, v2.y, v2.z, v2.w,
                           v3.x, v3.y, v3.z, v3.w };

    float acc0 = 0.0f, acc1 = 0.0f;   // two chains for ILP
#pragma unroll
    for (int j = 0; j < 16; ++j) {
        const float v = vv[j];
#pragma unroll
        for (int k = 0; k < MP; k += 2) {
            acc0 += fmaxf(0.0f, v - th[k]);
            acc1 += fmaxf(0.0f, v - th[k + 1]);
        }
    }
    float acc = acc0 + acc1;

    // wave (64-lane) shuffle reduce
#pragma unroll
    for (int off = 32; off > 0; off >>= 1)
        acc += __shfl_down(acc, off, 64);

    __shared__ float s_part[4];
    const int wave = t >> 6;
    if ((t & 63) == 0) s_part[wave] = acc;
    __syncthreads();

    if (t == 0) {
        const float total = s_part[0] + s_part[1] + s_part[2] + s_part[3];
        // Correction: contribution of the positive columns (dedup duplicates,
        // since y[i,d]=1 regardless of how many times d appears in pos_ids).
        float corr = 0.0f;
#pragma unroll
        for (int k = 0; k < MP; ++k) {
            bool dup = false;
#pragma unroll
            for (int k2 = 0; k2 < k; ++k2) dup = dup || (pi[k2] == pi[k]);
            if (!dup) {
                const float xk = th[k] + MARGIN;   // = x[i, pos_k]
#pragma unroll
                for (int j = 0; j < MP; ++j)
                    corr += fmaxf(0.0f, xk - th[j]);
            }
        }
        ws[row] = total - corr;
    }
}

// Stage 2: one block reduces MB partials (double accumulation) and scales.
__global__ __launch_bounds__(256) void margin_final_kernel(
    const float* __restrict__ ws,
    float* __restrict__ out)
{
    const int t = threadIdx.x;
    double acc = 0.0;
#pragma unroll
    for (int it = 0; it < 16; ++it)
        acc += (double)ws[it * 256 + t];

#pragma unroll
    for (int off = 32; off > 0; off >>= 1)
        acc += __shfl_down(acc, off, 64);

    __shared__ double s_part[4];
    const int wave = t >> 6;
    if ((t & 63) == 0) s_part[wave] = acc;
    __syncthreads();
    if (t == 0) {
        const double tot = s_part[0] + s_part[1] + s_part[2] + s_part[3];
        const double count = (double)MB * (double)MP * (double)(MD - MP);
        out[0] = (float)(tot / count);
    }
}

extern "C" void kernel_launch(void* const* d_in, const int* in_sizes, int n_in,
                              void* d_out, int out_size, void* d_ws, size_t ws_size,
                              hipStream_t stream) {
    const float* x = (const float*)d_in[0];
    // d_in[1] is y, redundant with pos_ids — not read (halves HBM traffic).
    const int* pos_ids = (const int*)d_in[2];
    float* out = (float*)d_out;
    float* ws = (float*)d_ws;  // MB floats = 16 KB of scratch

    margin_rows_kernel<<<MB, 256, 0, stream>>>(x, pos_ids, ws);
    margin_final_kernel<<<1, 256, 0, stream>>>(ws, out);
}